// Round 8
// baseline (307.570 us; speedup 1.0000x reference)
//
#include <hip/hip_runtime.h>
#include <stdint.h>

#define DEV __device__ __forceinline__

typedef __attribute__((ext_vector_type(8))) __bf16 bf16x8;
typedef __attribute__((ext_vector_type(4))) float floatx4;

DEV unsigned int f2bf(float f) {
  union { float f; unsigned int i; } x; x.f = f;
  unsigned int r = x.i + 0x7FFFu + ((x.i >> 16) & 1u);
  return r >> 16;
}
DEV void gl2lds16(const unsigned short* g, unsigned short* l) {
  __builtin_amdgcn_global_load_lds(
      (const __attribute__((address_space(1))) unsigned int*)g,
      (__attribute__((address_space(3))) unsigned int*)l, 16, 0, 0);
}
DEV floatx4 zero4() { floatx4 z; z[0]=0.f; z[1]=0.f; z[2]=0.f; z[3]=0.f; return z; }

DEV void bar() {
  asm volatile("" ::: "memory");
  __builtin_amdgcn_s_barrier();
  asm volatile("" ::: "memory");
}
#define VMCNT6 asm volatile("s_waitcnt vmcnt(6)" ::: "memory")
#define VMCNT0 asm volatile("s_waitcnt vmcnt(0)" ::: "memory")

// ---- merged prep, ILP-rebuilt (G13): grid 4159 blocks -----------------------
__global__ void cca_prep_k(const float* __restrict__ W0, const float* __restrict__ W1,
                           const float* __restrict__ W2, const float* __restrict__ W3,
                           unsigned short* __restrict__ D0, unsigned short* __restrict__ D1,
                           unsigned short* __restrict__ D2, unsigned short* __restrict__ D3,
                           const float* __restrict__ e, unsigned short* __restrict__ eb,
                           const float* __restrict__ h, const float* __restrict__ g,
                           unsigned short* __restrict__ hn, float* __restrict__ out) {
  __shared__ float tile[64][65];
  int blk = blockIdx.x;
  int t = threadIdx.x;
  if (blk < 1024) {                       // weight transpose, 64x64 tile
    const float* W; unsigned short* Wt;
    switch (blk >> 8) {
      case 0: W = W0; Wt = D0; break;
      case 1: W = W1; Wt = D1; break;
      case 2: W = W2; Wt = D2; break;
      default: W = W3; Wt = D3; break;
    }
    int k0 = (blk & 15) * 64, n0 = ((blk >> 4) & 15) * 64;
    int c = t & 63, r4 = t >> 6;
#pragma unroll
    for (int it = 0; it < 16; ++it) {
      int r = it * 4 + r4;
      tile[r][c] = W[(size_t)(k0 + r) * 1024 + n0 + c];
    }
    __syncthreads();
#pragma unroll
    for (int it = 0; it < 16; ++it) {
      int r = it * 4 + r4;
      Wt[(size_t)(n0 + r) * 1024 + k0 + c] = (unsigned short)f2bf(tile[c][r]);
    }
    return;
  }
  if (blk < 3072) {                       // e f32 -> bf16, 8 float4/thread
    int base = (blk - 1024) * 256 + t;    // [0, 524288)
    const float4* e4 = (const float4*)e;
    uint2* eb2 = (uint2*)eb;
#pragma unroll
    for (int j = 0; j < 8; ++j) {
      int i = base + j * 524288;          // 8*524288 = 4194304 float4s = all of e
      float4 v = e4[i];
      uint2 o;
      o.x = f2bf(v.x) | (f2bf(v.y) << 16);
      o.y = f2bf(v.z) | (f2bf(v.w) << 16);
      eb2[i] = o;
    }
    return;
  }
  if (blk < 4096) {                       // rmsnorm: wave-per-row, 4 rows/block
    int lane = t & 63, wv = t >> 6;
    int row = (blk - 3072) * 4 + wv;      // 0..4095
    int b = row >> 10, p = row & 1023;
    uint2* dst2 = (uint2*)(hn + (size_t)row * 1024);
    if (p >= 961) {
      uint2 z; z.x = 0u; z.y = 0u;
#pragma unroll
      for (int j = 0; j < 4; ++j) dst2[lane + j * 64] = z;
      return;
    }
    const float4* src = (const float4*)(h + ((size_t)(b << 10) + p + 63) * 1024);
    const float4* g4 = (const float4*)g;
    float4 v[4];
    float ss = 0.f;
#pragma unroll
    for (int j = 0; j < 4; ++j) {
      v[j] = src[lane + j * 64];
      ss += v[j].x * v[j].x + v[j].y * v[j].y + v[j].z * v[j].z + v[j].w * v[j].w;
    }
#pragma unroll
    for (int m = 32; m > 0; m >>= 1) ss += __shfl_xor(ss, m);
    float r = rsqrtf(ss * (1.0f / 1024.0f) + 1e-8f);
#pragma unroll
    for (int j = 0; j < 4; ++j) {
      float4 gv = g4[lane + j * 64];
      uint2 o;
      o.x = f2bf(v[j].x * gv.x * r) | (f2bf(v[j].y * gv.y * r) << 16);
      o.y = f2bf(v[j].z * gv.z * r) | (f2bf(v[j].w * gv.w * r) << 16);
      dst2[lane + j * 64] = o;
    }
    return;
  }
  {                                        // head copy, 4 float4/thread
#pragma unroll
    for (int j = 0; j < 4; ++j) {
      int idx = (blk - 4096) * 1024 + j * 256 + t;   // < 64512 by construction
      int e4i = idx * 4;
      int b = e4i / 64512;                 // 63*1024
      int r = e4i - b * 64512;
      size_t off = (size_t)b * 1024 * 1024 + (size_t)r;
      *(float4*)(out + off) = *(const float4*)(h + off);
    }
  }
}

// ---- merged QKV GEMM: 256x256 tile, BK=64, 8 waves, 8-phase schedule -------
// RETRY of the round-1/2 template with the register-budget fix:
// __launch_bounds__(512, 1) -> 2 waves/SIMD -> 256 VGPR/wave. The round-1/2
// failure (150us, MfmaUtil 20%) was (512,2) capping VGPR at 128 < the ~206
// live set -> acc[8][4] spilled (WRITE_SIZE 92.5 vs 73.7 MB = +19MB scratch).
// Schedule itself passed correctness both times; ledger re-verified:
//   prologue 14 loads, VMCNT6 retires buf0's 8. Steady state: 6 outstanding
//   entering P1; P4 VMCNT6 retires {pre-iter 6, P1's 2} = buf1 cur (covers
//   P5-P7); P8 VMCNT6 retires P2-P5's 8 = buf0 next (covers next P1).
//   Every LDS write lands >=1 barrier-separated phase after region's last read.
// KV blocks [0,512): x=blk&7 (XCD, 512%8==0 bijective), s=blk>>3,
//   mblk=x*8+(s&7), nblk=s>>3; nblk<4 -> K half; nblk>=4 -> V half (VT image).
// Q blocks [512,576): q=blk-512, x=q&7, s=q>>3, mblk=x*2+(s&1), nblk=s>>1.
__launch_bounds__(512, 1)
__global__ void cca_gemmQKV_k(const unsigned short* __restrict__ eb,
                              const unsigned short* __restrict__ WkvT,
                              const float* __restrict__ bk,
                              const float* __restrict__ bv,
                              unsigned short* __restrict__ KVb,
                              const unsigned short* __restrict__ hn,
                              const unsigned short* __restrict__ WqT,
                              const float* __restrict__ bq,
                              unsigned short* __restrict__ Qb) {
  __shared__ unsigned short smem[65536];   // 128 KB: A0|B0|A1|B1, reused as VT image
  int blk = blockIdx.x;
  const unsigned short *A, *Bt;
  int tM, tN;
  bool isQ = (blk >= 512), isV = false;
  if (!isQ) {
    int x = blk & 7, s = blk >> 3;        // s 0..63
    int mblk = x * 8 + (s & 7), nblk = s >> 3;
    tM = mblk * 256; tN = nblk * 256; isV = (nblk >= 4);
    A = eb; Bt = WkvT;
  } else {
    int q = blk - 512;
    int x = q & 7, s = q >> 3;            // s 0..7
    int mblk = x * 2 + (s & 1), nblk = s >> 1;
    tM = mblk * 256; tN = nblk * 256;
    A = hn; Bt = WqT;
  }
  const int t = threadIdx.x, lane = t & 63, wv = t >> 6;
  const int wm = wv >> 2, wn = wv & 3;     // 2 M-waves x 4 N-waves; wave tile 128x64
  const int l15 = lane & 15, quad = lane >> 4;
  const int arow = lane >> 3;
  const int gchk = (lane & 7) ^ arow;      // pre-swizzled global source unit

  unsigned short* Ab0 = smem;
  unsigned short* Bb0 = smem + 16384;
  unsigned short* Ab1 = smem + 32768;
  unsigned short* Bb1 = smem + 49152;

  auto stA = [&](unsigned short* lds, int k0, int hf) {
    int r0 = hf * 64 + wv * 8;
    gl2lds16(A + (size_t)(tM + r0 + arow) * 1024 + k0 + gchk * 8, lds + r0 * 64);
    int r1 = 128 + hf * 64 + wv * 8;
    gl2lds16(A + (size_t)(tM + r1 + arow) * 1024 + k0 + gchk * 8, lds + r1 * 64);
  };
  auto stB = [&](unsigned short* lds, int k0, int hf) {
    int g = wv >> 1;
#pragma unroll
    for (int ii = 0; ii < 2; ++ii) {
      int r0 = g * 64 + hf * 32 + ((wv & 1) * 2 + ii) * 8;
      gl2lds16(Bt + (size_t)(tN + r0 + arow) * 1024 + k0 + gchk * 8, lds + r0 * 64);
    }
  };

  floatx4 acc[8][4];
#pragma unroll
  for (int i = 0; i < 8; ++i)
#pragma unroll
    for (int j = 0; j < 4; ++j) acc[i][j] = zero4();

  bf16x8 af[4][2], bf0[2][2], bf1[2][2];

  auto ldA = [&](const unsigned short* Ab, int mq) {
#pragma unroll
    for (int mt = 0; mt < 4; ++mt) {
      int r = wm * 128 + mq * 64 + mt * 16 + l15;
#pragma unroll
      for (int h = 0; h < 2; ++h) {
        int u = h * 4 + quad;
        af[mt][h] = *(const bf16x8*)&Ab[r * 64 + ((u ^ (l15 & 7)) << 3)];
      }
    }
  };
  auto ldB = [&](const unsigned short* Bb, bf16x8 (&bf)[2][2], int nq) {
#pragma unroll
    for (int nt = 0; nt < 2; ++nt) {
      int r = wn * 64 + nq * 32 + nt * 16 + l15;
#pragma unroll
      for (int h = 0; h < 2; ++h) {
        int u = h * 4 + quad;
        bf[nt][h] = *(const bf16x8*)&Bb[r * 64 + ((u ^ (l15 & 7)) << 3)];
      }
    }
  };
  auto mma = [&](bf16x8 (&bf)[2][2], int mq, int nq) {
    __builtin_amdgcn_s_setprio(1);
#pragma unroll
    for (int mt = 0; mt < 4; ++mt)
#pragma unroll
      for (int nt = 0; nt < 2; ++nt)
#pragma unroll
        for (int h = 0; h < 2; ++h)
          acc[mq * 4 + mt][nq * 2 + nt] = __builtin_amdgcn_mfma_f32_16x16x32_bf16(
              af[mt][h], bf[nt][h], acc[mq * 4 + mt][nq * 2 + nt], 0, 0, 0);
    __builtin_amdgcn_s_setprio(0);
  };

  // prologue: kt0 full -> buf0; kt1 A.h0,B.h0,B.h1 -> buf1 (A.h1 staged at P1)
  stA(Ab0, 0, 0); stA(Ab0, 0, 1);
  stB(Bb0, 0, 0); stB(Bb0, 0, 1);
  stA(Ab1, 64, 0); stB(Bb1, 64, 0); stB(Bb1, 64, 1);
  VMCNT6;                                  // oldest 8 = all of buf0 landed
  bar();

#pragma unroll 1
  for (int i = 0; i < 8; ++i) {
    int kA = (2 * i + 1) * 64;             // buf1 current (A.h1 late-stage)
    int kB = (2 * i + 2) * 64;             // buf0 next
    int kC = (2 * i + 3) * 64;             // buf1 next
    bool vB = (2 * i + 2) < 16, vC = (2 * i + 3) < 16;
    // P1
    ldA(Ab0, 0); ldB(Bb0, bf0, 0);
    stA(Ab1, kA, 1);
    bar(); mma(bf0, 0, 0); bar();
    // P2
    ldB(Bb0, bf1, 1);
    if (vB) stA(Ab0, kB, 0);
    bar(); mma(bf1, 0, 1); bar();
    // P3
    ldA(Ab0, 1);
    if (vB) stB(Bb0, kB, 0);
    bar(); mma(bf1, 1, 1); bar();
    // P4
    if (vB) { stB(Bb0, kB, 1); VMCNT6; } else { VMCNT0; }
    bar(); mma(bf0, 1, 0); bar();
    // P5
    ldA(Ab1, 0); ldB(Bb1, bf0, 0);
    if (vB) stA(Ab0, kB, 1);
    bar(); mma(bf0, 0, 0); bar();
    // P6
    ldB(Bb1, bf1, 1);
    if (vC) stA(Ab1, kC, 0);
    bar(); mma(bf1, 0, 1); bar();
    // P7
    ldA(Ab1, 1);
    if (vC) stB(Bb1, kC, 0);
    bar(); mma(bf1, 1, 1); bar();
    // P8
    if (vC) { stB(Bb1, kC, 1); VMCNT6; }
    bar(); mma(bf0, 1, 0); bar();
  }

  if (isV) {
    // Build the full 128 KB [4 heads][64 d][256 keys swizzled] image in LDS,
    // then copy out with coalesced uint4 stores. acc row mi -> key offset
    // (mi>>2)*64+(mi&3)*16; acc col ni -> d offset (ni>>1)*32+(ni&1)*16.
    int chunk = tM >> 8;                   // b*16+c (BM=256 == one chunk)
    int hbase = (tN - 1024) >> 6;          // first head of this tile
    const float* bvp = bv + (tN - 1024) + wn * 64;
    VMCNT0;                                // queue provably empty; defensive
    bar();                                 // all fragment reads done, smem reusable
#pragma unroll
    for (int ni = 0; ni < 4; ++ni) {
      int d = (ni >> 1) * 32 + (ni & 1) * 16 + l15;   // 0..63
      float bs = bvp[d];
      int d7 = d & 7;
      int dbase = wn * 16384 + d * 256 + (quad & 1) * 4;
#pragma unroll
      for (int mi = 0; mi < 8; ++mi) {
        int k8 = wm * 16 + (mi >> 2) * 8 + (mi & 3) * 2 + (quad >> 1);  // key>>3
        int off = dbase + ((k8 ^ d7) << 3);
        uint2 o;
        o.x = f2bf(acc[mi][ni][0] + bs) | (f2bf(acc[mi][ni][1] + bs) << 16);
        o.y = f2bf(acc[mi][ni][2] + bs) | (f2bf(acc[mi][ni][3] + bs) << 16);
        *(uint2*)&smem[off] = o;
      }
    }
    bar();
    unsigned short* vdst = KVb + (size_t)chunk * 524288 + 1024;
#pragma unroll
    for (int it = 0; it < 16; ++it) {
      int flat = it * 512 + t;             // 0..8191 16B units
      int h = flat >> 11;                  // head local 0..3
      int g = flat & 2047;                 // unit within head
      size_t dst = (size_t)((hbase + h) * 16 + (g >> 7)) * 2048 + (g & 127) * 8;
      *(uint4*)(vdst + dst) = *(const uint4*)&smem[h * 16384 + g * 8];
    }
    return;
  }
#pragma unroll
  for (int mi = 0; mi < 8; ++mi) {
    int mrow = tM + wm * 128 + (mi >> 2) * 64 + (mi & 3) * 16 + quad * 4;
#pragma unroll
    for (int ni = 0; ni < 4; ++ni) {
      int ncol = tN + wn * 64 + (ni >> 1) * 32 + (ni & 1) * 16 + l15;
      float bs = isQ ? bq[ncol] : bk[ncol];
#pragma unroll
      for (int r = 0; r < 4; ++r) {
        int m = mrow + r;
        if (isQ) Qb[(size_t)m * 1024 + ncol] = (unsigned short)f2bf(acc[mi][ni][r] + bs);
        else     KVb[(size_t)m * 2048 + ncol] = (unsigned short)f2bf(acc[mi][ni][r] + bs);
      }
    }
  }
}

// ---- O-proj GEMM: 64x64 tile, BK=128 (two 64-col panels per barrier pair) --
__launch_bounds__(256, 4)
__global__ void cca_gemmO_k(const unsigned short* __restrict__ A,   // Ob bf16
                            const unsigned short* __restrict__ Bt,  // WoT bf16
                            const float* __restrict__ bias,
                            const float* __restrict__ resid,
                            float* __restrict__ out) {
  __shared__ unsigned short AshL[64 * 64], AshH[64 * 64];
  __shared__ unsigned short BshL[64 * 64], BshH[64 * 64];
  int tM = blockIdx.x * 64, tN = blockIdx.y * 64;
  int t = threadIdx.x, lane = t & 63, wv = t >> 6;
  int wm = wv >> 1, wn = wv & 1;              // 2x2 waves, wave tile 32x32
  int l15 = lane & 15, quad = lane >> 4;
  int arow = lane >> 3, achk = lane & 7;
  int gchk = achk ^ arow;
  floatx4 acc[2][2];
#pragma unroll
  for (int i = 0; i < 2; ++i)
#pragma unroll
    for (int j = 0; j < 2; ++j) acc[i][j] = zero4();

  for (int k0 = 0; k0 < 1024; k0 += 128) {
    __syncthreads();
#pragma unroll
    for (int ii = 0; ii < 2; ++ii) {
      int seg = ii * 4 + wv;                 // 0..7, 8 rows each
      int row = seg * 8 + arow;
      gl2lds16(A + (size_t)(tM + row) * 1024 + k0 + gchk * 8, AshL + seg * 512);
      gl2lds16(A + (size_t)(tM + row) * 1024 + k0 + 64 + gchk * 8, AshH + seg * 512);
      gl2lds16(Bt + (size_t)(tN + row) * 1024 + k0 + gchk * 8, BshL + seg * 512);
      gl2lds16(Bt + (size_t)(tN + row) * 1024 + k0 + 64 + gchk * 8, BshH + seg * 512);
    }
    __syncthreads();
#pragma unroll
    for (int pan = 0; pan < 2; ++pan) {
      const unsigned short* Ap = pan ? AshH : AshL;
      const unsigned short* Bp = pan ? BshH : BshL;
#pragma unroll
      for (int hseg = 0; hseg < 2; ++hseg) {
        int u = (hseg << 2) | quad;
        bf16x8 af[2], bfv[2];
#pragma unroll
        for (int mt = 0; mt < 2; ++mt) {
          int r = wm * 32 + mt * 16 + l15;
          af[mt] = *(const bf16x8*)&Ap[r * 64 + ((u ^ (l15 & 7)) << 3)];
        }
#pragma unroll
        for (int nt = 0; nt < 2; ++nt) {
          int r = wn * 32 + nt * 16 + l15;
          bfv[nt] = *(const bf16x8*)&Bp[r * 64 + ((u ^ (l15 & 7)) << 3)];
        }
#pragma unroll
        for (int mt = 0; mt < 2; ++mt)
#pragma unroll
          for (int nt = 0; nt < 2; ++nt)
            acc[mt][nt] = __builtin_amdgcn_mfma_f32_16x16x32_bf16(af[mt], bfv[nt], acc[mt][nt], 0, 0, 0);
      }
    }
  }

#pragma unroll
  for (int mt = 0; mt < 2; ++mt) {
    int mrow = tM + wm * 32 + mt * 16 + quad * 4;
#pragma unroll
    for (int nt = 0; nt < 2; ++nt) {
      int ncol = tN + wn * 32 + nt * 16 + l15;
      float bs = bias[ncol];
#pragma unroll
      for (int r = 0; r < 4; ++r) {
        int m = mrow + r;
        int p = m & 1023;
        if (p < 961) {
          size_t o = (size_t)(m + 63) * 1024 + (size_t)ncol;
          out[o] = acc[mt][nt][r] + bs + resid[o];
        }
      }
    }
  }
}

// ---------------- attention: one block per (b, c, head), 4 blocks/CU --------
// T2 swizzle (kept — worth ~11 us): Q/K staged with pre-swizzled global
// source (unit chk^rowi) and read at unit (u ^ (l15&7)).
__launch_bounds__(256, 4)
__global__ void cca_attn_k(const unsigned short* __restrict__ Q,   // [4096][1024]
                           const unsigned short* __restrict__ KV,  // K cols + VT region
                           unsigned short* __restrict__ O) {       // [4096][1024]
  __shared__ unsigned short smemA[64 * 64 + 256 * 64];   // Qsh|Ksh, aliased by Psh
  unsigned short* Qsh = smemA;
  unsigned short* Ksh = smemA + 64 * 64;
  unsigned short* Psh = smemA;                // alias (post-barrier); 64*264 fits
  int bch = blockIdx.x;
  int hh = bch & 15, c = (bch >> 4) & 15, b = bch >> 8;
  int t = threadIdx.x, lane = t & 63, wv = t >> 6;
  int l15 = lane & 15, quad = lane >> 4;
  size_t qbase = (size_t)b * 1024 + (size_t)c * 64;
  size_t kvbase = (size_t)b * 4096 + (size_t)c * 256;
  int hoff = hh * 64;
  const unsigned short* vbase2 =
      KV + (size_t)(b * 16 + c) * 524288 + 1024 + (size_t)hh * 32768;

  {
    int rowi = lane >> 3, chk = lane & 7;
    int gchk2 = chk ^ rowi;                // pre-swizzled source unit (T2)
#pragma unroll
    for (int ii = 0; ii < 2; ++ii) {
      int seg = wv + ii * 4;
      int row = seg * 8 + rowi;            // row&7 == rowi
      gl2lds16(Q + (qbase + row) * 1024 + hoff + gchk2 * 8, Qsh + seg * 512);
    }
#pragma unroll
    for (int ii = 0; ii < 8; ++ii) {
      int seg = wv + ii * 4;
      int row = seg * 8 + rowi;
      gl2lds16(KV + (kvbase + row) * 2048 + hoff + gchk2 * 8, Ksh + seg * 512);
    }
  }
  __syncthreads();

  floatx4 st[16];
#pragma unroll
  for (int i = 0; i < 16; ++i) st[i] = zero4();
  // swizzled fragment reads: LDS unit (u ^ (row&7)), row&7 == l15&7
  int sw0 = (quad ^ (l15 & 7)) << 3;         // u = quad
  int sw1 = ((quad + 4) ^ (l15 & 7)) << 3;   // u = quad+4
  bf16x8 a0 = *(const bf16x8*)&Qsh[(wv * 16 + l15) * 64 + sw0];
  bf16x8 a1 = *(const bf16x8*)&Qsh[(wv * 16 + l15) * 64 + sw1];
  __builtin_amdgcn_s_setprio(1);
#pragma unroll
  for (int kt = 0; kt < 16; ++kt) {
    bf16x8 b0 = *(const bf16x8*)&Ksh[(kt * 16 + l15) * 64 + sw0];
    bf16x8 b1 = *(const bf16x8*)&Ksh[(kt * 16 + l15) * 64 + sw1];
    st[kt] = __builtin_amdgcn_mfma_f32_16x16x32_bf16(a0, b0, st[kt], 0, 0, 0);
    st[kt] = __builtin_amdgcn_mfma_f32_16x16x32_bf16(a1, b1, st[kt], 0, 0, 0);
  }
  __builtin_amdgcn_s_setprio(0);
  __syncthreads();   // Qsh/Ksh dead; Psh may alias

  const float scale = 0.125f;  // 1/sqrt(64)
#pragma unroll
  for (int r = 0; r < 4; ++r) {
    float mx = -1e30f;
#pragma unroll
    for (int kt = 0; kt < 16; ++kt) mx = fmaxf(mx, st[kt][r]);
    mx = fmaxf(mx, __shfl_xor(mx, 1));
    mx = fmaxf(mx, __shfl_xor(mx, 2));
    mx = fmaxf(mx, __shfl_xor(mx, 4));
    mx = fmaxf(mx, __shfl_xor(mx, 8));
    float sum = 0.f;
#pragma unroll
    for (int kt = 0; kt < 16; ++kt) {
      float e = __expf((st[kt][r] - mx) * scale);
      st[kt][r] = e;
      sum += e;
    }
    sum += __shfl_xor(sum, 1);
    sum += __shfl_xor(sum, 2);
    sum += __shfl_xor(sum, 4);
    sum += __shfl_xor(sum, 8);
    float inv = 1.0f / sum;
    int prow = wv * 16 + quad * 4 + r;
#pragma unroll
    for (int kt = 0; kt < 16; ++kt)
      Psh[prow * 264 + kt * 16 + l15] = (unsigned short)f2bf(st[kt][r] * inv);
  }
  __syncthreads();   // P visible to all waves

  auto vload = [&](int kt2, int nt) -> bf16x8 {
    int vrow = nt * 16 + l15;
    int u = kt2 * 4 + quad;
    int i = vrow * 256 + ((u ^ (vrow & 7)) << 3);
    return *(const bf16x8*)(vbase2 + i + (i & ~1023));
  };

  floatx4 ot[4];
#pragma unroll
  for (int nt = 0; nt < 4; ++nt) ot[nt] = zero4();
  bf16x8 bvA[4], bvB[4];
#pragma unroll
  for (int nt = 0; nt < 4; ++nt) bvA[nt] = vload(0, nt);
#pragma unroll
  for (int kt2 = 0; kt2 < 8; kt2 += 2) {
#pragma unroll
    for (int nt = 0; nt < 4; ++nt) bvB[nt] = vload(kt2 + 1, nt);
    bf16x8 ap0 = *(const bf16x8*)&Psh[(wv * 16 + l15) * 264 + kt2 * 32 + quad * 8];
    __builtin_amdgcn_s_setprio(1);
#pragma unroll
    for (int nt = 0; nt < 4; ++nt)
      ot[nt] = __builtin_amdgcn_mfma_f32_16x16x32_bf16(ap0, bvA[nt], ot[nt], 0, 0, 0);
    __builtin_amdgcn_s_setprio(0);
    if (kt2 + 2 < 8) {
#pragma unroll
      for (int nt = 0; nt < 4; ++nt) bvA[nt] = vload(kt2 + 2, nt);
    }
    bf16x8 ap1 = *(const bf16x8*)&Psh[(wv * 16 + l15) * 264 + (kt2 + 1) * 32 + quad * 8];
    __builtin_amdgcn_s_setprio(1);
#pragma unroll
    for (int nt = 0; nt < 4; ++nt)
      ot[nt] = __builtin_amdgcn_mfma_f32_16x16x32_bf16(ap1, bvB[nt], ot[nt], 0, 0, 0);
    __builtin_amdgcn_s_setprio(0);
  }
#pragma unroll
  for (int nt = 0; nt < 4; ++nt) {
#pragma unroll
    for (int r = 0; r < 4; ++r) {
      int i = wv * 16 + quad * 4 + r;
      int dcol = hoff + nt * 16 + l15;
      O[(qbase + i) * 1024 + dcol] = (unsigned short)f2bf(ot[nt][r]);
    }
  }
}

extern "C" void kernel_launch(void* const* d_in, const int* in_sizes, int n_in,
                              void* d_out, int out_size, void* d_ws, size_t ws_size,
                              hipStream_t stream) {
  const float* h  = (const float*)d_in[0];
  const float* e  = (const float*)d_in[1];
  const float* g  = (const float*)d_in[2];
  const float* Wq = (const float*)d_in[3];
  const float* bq = (const float*)d_in[4];
  const float* Wk = (const float*)d_in[5];
  const float* bk = (const float*)d_in[6];
  const float* Wv = (const float*)d_in[7];
  const float* bv = (const float*)d_in[8];
  const float* Wo = (const float*)d_in[9];
  const float* bo = (const float*)d_in[10];
  float* out = (float*)d_out;

  unsigned short* ws   = (unsigned short*)d_ws;
  unsigned short* hn   = ws;                                   // 4096*1024
  unsigned short* WqT  = hn   + (size_t)4096 * 1024;           // 1024*1024
  unsigned short* WkvT = WqT  + (size_t)1024 * 1024;           // 2048*1024
  unsigned short* WoT  = WkvT + (size_t)2048 * 1024;           // 1024*1024
  unsigned short* Qb   = WoT  + (size_t)1024 * 1024;           // 4096*1024
  unsigned short* KVb  = Qb   + (size_t)4096 * 1024;           // 16384*2048
  unsigned short* Ob   = KVb  + (size_t)16384 * 2048;          // 4096*1024
  unsigned short* eb   = Ob   + (size_t)4096 * 1024;           // 16384*1024

  cca_prep_k<<<4159, 256, 0, stream>>>(
      Wq, Wk, Wv, Wo, WqT, WkvT, WkvT + (size_t)1024 * 1024, WoT,
      e, eb, h, g, hn, out);

  cca_gemmQKV_k<<<576, 512, 0, stream>>>(eb, WkvT, bk, bv, KVb,
                                         hn, WqT, bq, Qb);

  cca_attn_k<<<1024, 256, 0, stream>>>(Qb, KVb, Ob);

  cca_gemmO_k<<<dim3(64, 16), 256, 0, stream>>>(Ob, WoT, bo, h, out);
}

// Round 9
// 262.579 us; speedup vs baseline: 1.1713x; 1.1713x over previous
//
#include <hip/hip_runtime.h>
#include <stdint.h>

#define DEV __device__ __forceinline__

typedef __attribute__((ext_vector_type(8))) __bf16 bf16x8;
typedef __attribute__((ext_vector_type(4))) float floatx4;

DEV unsigned int f2bf(float f) {
  union { float f; unsigned int i; } x; x.f = f;
  unsigned int r = x.i + 0x7FFFu + ((x.i >> 16) & 1u);
  return r >> 16;
}
DEV void gl2lds16(const unsigned short* g, unsigned short* l) {
  __builtin_amdgcn_global_load_lds(
      (const __attribute__((address_space(1))) unsigned int*)g,
      (__attribute__((address_space(3))) unsigned int*)l, 16, 0, 0);
}
DEV floatx4 zero4() { floatx4 z; z[0]=0.f; z[1]=0.f; z[2]=0.f; z[3]=0.f; return z; }

// ---- merged prep, ILP-rebuilt (G13): grid 4159 blocks -----------------------
__global__ void cca_prep_k(const float* __restrict__ W0, const float* __restrict__ W1,
                           const float* __restrict__ W2, const float* __restrict__ W3,
                           unsigned short* __restrict__ D0, unsigned short* __restrict__ D1,
                           unsigned short* __restrict__ D2, unsigned short* __restrict__ D3,
                           const float* __restrict__ e, unsigned short* __restrict__ eb,
                           const float* __restrict__ h, const float* __restrict__ g,
                           unsigned short* __restrict__ hn, float* __restrict__ out) {
  __shared__ float tile[64][65];
  int blk = blockIdx.x;
  int t = threadIdx.x;
  if (blk < 1024) {                       // weight transpose, 64x64 tile
    const float* W; unsigned short* Wt;
    switch (blk >> 8) {
      case 0: W = W0; Wt = D0; break;
      case 1: W = W1; Wt = D1; break;
      case 2: W = W2; Wt = D2; break;
      default: W = W3; Wt = D3; break;
    }
    int k0 = (blk & 15) * 64, n0 = ((blk >> 4) & 15) * 64;
    int c = t & 63, r4 = t >> 6;
#pragma unroll
    for (int it = 0; it < 16; ++it) {
      int r = it * 4 + r4;
      tile[r][c] = W[(size_t)(k0 + r) * 1024 + n0 + c];
    }
    __syncthreads();
#pragma unroll
    for (int it = 0; it < 16; ++it) {
      int r = it * 4 + r4;
      Wt[(size_t)(n0 + r) * 1024 + k0 + c] = (unsigned short)f2bf(tile[c][r]);
    }
    return;
  }
  if (blk < 3072) {                       // e f32 -> bf16, 8 float4/thread
    int base = (blk - 1024) * 256 + t;    // [0, 524288)
    const float4* e4 = (const float4*)e;
    uint2* eb2 = (uint2*)eb;
#pragma unroll
    for (int j = 0; j < 8; ++j) {
      int i = base + j * 524288;          // 8*524288 = 4194304 float4s = all of e
      float4 v = e4[i];
      uint2 o;
      o.x = f2bf(v.x) | (f2bf(v.y) << 16);
      o.y = f2bf(v.z) | (f2bf(v.w) << 16);
      eb2[i] = o;
    }
    return;
  }
  if (blk < 4096) {                       // rmsnorm: wave-per-row, 4 rows/block
    int lane = t & 63, wv = t >> 6;
    int row = (blk - 3072) * 4 + wv;      // 0..4095
    int b = row >> 10, p = row & 1023;
    uint2* dst2 = (uint2*)(hn + (size_t)row * 1024);
    if (p >= 961) {
      uint2 z; z.x = 0u; z.y = 0u;
#pragma unroll
      for (int j = 0; j < 4; ++j) dst2[lane + j * 64] = z;
      return;
    }
    const float4* src = (const float4*)(h + ((size_t)(b << 10) + p + 63) * 1024);
    const float4* g4 = (const float4*)g;
    float4 v[4];
    float ss = 0.f;
#pragma unroll
    for (int j = 0; j < 4; ++j) {
      v[j] = src[lane + j * 64];
      ss += v[j].x * v[j].x + v[j].y * v[j].y + v[j].z * v[j].z + v[j].w * v[j].w;
    }
#pragma unroll
    for (int m = 32; m > 0; m >>= 1) ss += __shfl_xor(ss, m);
    float r = rsqrtf(ss * (1.0f / 1024.0f) + 1e-8f);
#pragma unroll
    for (int j = 0; j < 4; ++j) {
      float4 gv = g4[lane + j * 64];
      uint2 o;
      o.x = f2bf(v[j].x * gv.x * r) | (f2bf(v[j].y * gv.y * r) << 16);
      o.y = f2bf(v[j].z * gv.z * r) | (f2bf(v[j].w * gv.w * r) << 16);
      dst2[lane + j * 64] = o;
    }
    return;
  }
  {                                        // head copy, 4 float4/thread
#pragma unroll
    for (int j = 0; j < 4; ++j) {
      int idx = (blk - 4096) * 1024 + j * 256 + t;   // < 64512 by construction
      int e4i = idx * 4;
      int b = e4i / 64512;                 // 63*1024
      int r = e4i - b * 64512;
      size_t off = (size_t)b * 1024 * 1024 + (size_t)r;
      *(float4*)(out + off) = *(const float4*)(h + off);
    }
  }
}

// ---- merged QKV GEMM, XCD-aware swizzle, fused LDS-staged VT epilogue ------
// (verified 916 TF structure: 128x128 tile, 4 waves, 4 blocks/CU. FINAL.
//  Session post-mortems — do not revisit:
//  * (256,5): VGPR cap 48 -> acc spill, WRITE 73.7->402 MB, 201 us (r6).
//  * 256^2 8-phase, (512,2): VGPR cap 128 -> partial spill, 150 us (r1/2).
//  * 256^2 8-phase, (512,1): STILL 128 VGPR + 21 MB spill, 129 us (r8).
//  The 2-barrier loop + 4 blocks/CU cross-block overlap (m114) is this
//  kernel's ceiling: 84.5 us, MfmaUtil 41%, 916 TF.)
// KV blocks [0,2048): x=blk&7 (XCD), s=blk>>3, mblk=x*16+(s&15), n=s>>4.
//   n<8 -> K half; n>=8 -> V half stored transposed+swizzled: VT elem
//   i(=d*256+((u^(d&7))<<3)+(key&7)) of (chunk,hh) lives at
//   KVb[chunk*524288 + (hh*16+(i>>10))*2048 + 1024 + (i&1023)].
// Q blocks [2048,2304): x=q&7, s=q>>3, mblk=x*4+(s&3), n=s>>2 -> Qb.
__launch_bounds__(256, 4)
__global__ void cca_gemmQKV_k(const unsigned short* __restrict__ eb,
                              const unsigned short* __restrict__ WkvT,
                              const float* __restrict__ bk,
                              const float* __restrict__ bv,
                              unsigned short* __restrict__ KVb,
                              const unsigned short* __restrict__ hn,
                              const unsigned short* __restrict__ WqT,
                              const float* __restrict__ bq,
                              unsigned short* __restrict__ Qb) {
  __shared__ unsigned short smem[128 * 64 * 2];   // Ash | Bsh, reused as VTsh
  unsigned short* Ash = smem;
  unsigned short* Bsh = smem + 128 * 64;
  int blk = blockIdx.x;
  const unsigned short *A, *Bt;
  int tM, tN;
  bool isQ = (blk >= 2048), isV = false;
  if (!isQ) {
    int x = blk & 7, s = blk >> 3;
    int mblk = x * 16 + (s & 15), n = s >> 4;
    tM = mblk * 128; tN = n * 128; isV = (n >= 8);
    A = eb; Bt = WkvT;
  } else {
    int q = blk - 2048;
    int x = q & 7, s = q >> 3;
    int mblk = x * 4 + (s & 3), n = s >> 2;
    tM = mblk * 128; tN = n * 128;
    A = hn; Bt = WqT;
  }
  int t = threadIdx.x, lane = t & 63, wv = t >> 6;
  int wm = wv >> 1, wn = wv & 1;
  int l15 = lane & 15, quad = lane >> 4;
  int arow = lane >> 3, achk = lane & 7;     // staging: 8 lanes / 128B row
  int gchk = achk ^ arow;                    // 3-bit XOR swizzled source unit
  floatx4 acc[4][4];
#pragma unroll
  for (int i = 0; i < 4; ++i)
#pragma unroll
    for (int j = 0; j < 4; ++j) acc[i][j] = zero4();

  for (int k0 = 0; k0 < 1024; k0 += 64) {
    __syncthreads();
#pragma unroll
    for (int ii = 0; ii < 4; ++ii) {
      int seg = ii * 4 + wv;                 // 0..15, 8 rows each
      int row = seg * 8 + arow;
      gl2lds16(A + (size_t)(tM + row) * 1024 + k0 + gchk * 8, Ash + seg * 512);
      gl2lds16(Bt + (size_t)(tN + row) * 1024 + k0 + gchk * 8, Bsh + seg * 512);
    }
    __syncthreads();
#pragma unroll
    for (int hseg = 0; hseg < 2; ++hseg) {
      int u = (hseg << 2) | quad;
      bf16x8 af[4], bfv[4];
#pragma unroll
      for (int mt = 0; mt < 4; ++mt) {
        int r = wm * 64 + mt * 16 + l15;
        af[mt] = *(const bf16x8*)&Ash[r * 64 + ((u ^ (l15 & 7)) << 3)];
      }
#pragma unroll
      for (int nt = 0; nt < 4; ++nt) {
        int r = wn * 64 + nt * 16 + l15;
        bfv[nt] = *(const bf16x8*)&Bsh[r * 64 + ((u ^ (l15 & 7)) << 3)];
      }
#pragma unroll
      for (int mt = 0; mt < 4; ++mt)
#pragma unroll
        for (int nt = 0; nt < 4; ++nt)
          acc[mt][nt] = __builtin_amdgcn_mfma_f32_16x16x32_bf16(af[mt], bfv[nt], acc[mt][nt], 0, 0, 0);
    }
  }

  if (isV) {
    // V half: build the 32 KB phys image [hhl(2)][d(64)][128 elems] in LDS,
    // then copy out with fully coalesced uint4 stores.
    int chunk = tM >> 8;                    // b*16+c
    int keybase = tM & 255;                 // 0 or 128
    int hh0 = (tN - 1024) >> 6;             // even head index base
    unsigned short* VTsh = smem;
    __syncthreads();                        // all fragment reads done
#pragma unroll
    for (int mt = 0; mt < 4; ++mt) {
      int kl = wm * 64 + mt * 16 + quad * 4;       // key local 0..127 (+r)
      int ul = kl >> 3;                            // local 16B unit 0..15
      int j0 = kl & 7;                             // 0 or 4
#pragma unroll
      for (int nt = 0; nt < 4; ++nt) {
        int d = nt * 16 + l15;                     // 0..63
        float bs = bv[(tN - 1024) + wn * 64 + d];
        int off = (wn * 64 + d) * 128 + ((ul ^ (d & 7)) << 3) + j0;
        uint2 o;
        o.x = f2bf(acc[mt][nt][0] + bs) | (f2bf(acc[mt][nt][1] + bs) << 16);
        o.y = f2bf(acc[mt][nt][2] + bs) | (f2bf(acc[mt][nt][3] + bs) << 16);
        *(uint2*)&VTsh[off] = o;
      }
    }
    __syncthreads();
    unsigned short* vdst = KVb + (size_t)chunk * 524288 + 1024;
#pragma unroll
    for (int it = 0; it < 8; ++it) {
      int flat = it * 256 + t;               // 0..2047 16B units
      int seg = flat >> 4;                   // 0..127 = hhl*64 + d
      int u16 = flat & 15;
      int hhl = seg >> 6, d = seg & 63;
      int hh = hh0 + hhl;
      size_t dst = (size_t)(hh * 16 + (d >> 2)) * 2048 +
                   (d & 3) * 256 + keybase + u16 * 8;
      *(uint4*)(vdst + dst) = *(const uint4*)&VTsh[seg * 128 + u16 * 8];
    }
    return;
  }
#pragma unroll
  for (int mt = 0; mt < 4; ++mt) {
    int mrow = tM + wm * 64 + mt * 16 + quad * 4;
#pragma unroll
    for (int nt = 0; nt < 4; ++nt) {
      int ncol = tN + wn * 64 + nt * 16 + l15;
      float bs = isQ ? bq[ncol] : bk[ncol];
#pragma unroll
      for (int r = 0; r < 4; ++r) {
        int m = mrow + r;
        if (isQ) Qb[(size_t)m * 1024 + ncol] = (unsigned short)f2bf(acc[mt][nt][r] + bs);
        else     KVb[(size_t)m * 2048 + ncol] = (unsigned short)f2bf(acc[mt][nt][r] + bs);
      }
    }
  }
}

// ---- O-proj GEMM: 64x64 tile, BK=128 (two 64-col panels per barrier pair) --
__launch_bounds__(256, 4)
__global__ void cca_gemmO_k(const unsigned short* __restrict__ A,   // Ob bf16
                            const unsigned short* __restrict__ Bt,  // WoT bf16
                            const float* __restrict__ bias,
                            const float* __restrict__ resid,
                            float* __restrict__ out) {
  __shared__ unsigned short AshL[64 * 64], AshH[64 * 64];
  __shared__ unsigned short BshL[64 * 64], BshH[64 * 64];
  int tM = blockIdx.x * 64, tN = blockIdx.y * 64;
  int t = threadIdx.x, lane = t & 63, wv = t >> 6;
  int wm = wv >> 1, wn = wv & 1;              // 2x2 waves, wave tile 32x32
  int l15 = lane & 15, quad = lane >> 4;
  int arow = lane >> 3, achk = lane & 7;
  int gchk = achk ^ arow;
  floatx4 acc[2][2];
#pragma unroll
  for (int i = 0; i < 2; ++i)
#pragma unroll
    for (int j = 0; j < 2; ++j) acc[i][j] = zero4();

  for (int k0 = 0; k0 < 1024; k0 += 128) {
    __syncthreads();
#pragma unroll
    for (int ii = 0; ii < 2; ++ii) {
      int seg = ii * 4 + wv;                 // 0..7, 8 rows each
      int row = seg * 8 + arow;
      gl2lds16(A + (size_t)(tM + row) * 1024 + k0 + gchk * 8, AshL + seg * 512);
      gl2lds16(A + (size_t)(tM + row) * 1024 + k0 + 64 + gchk * 8, AshH + seg * 512);
      gl2lds16(Bt + (size_t)(tN + row) * 1024 + k0 + gchk * 8, BshL + seg * 512);
      gl2lds16(Bt + (size_t)(tN + row) * 1024 + k0 + 64 + gchk * 8, BshH + seg * 512);
    }
    __syncthreads();
#pragma unroll
    for (int pan = 0; pan < 2; ++pan) {
      const unsigned short* Ap = pan ? AshH : AshL;
      const unsigned short* Bp = pan ? BshH : BshL;
#pragma unroll
      for (int hseg = 0; hseg < 2; ++hseg) {
        int u = (hseg << 2) | quad;
        bf16x8 af[2], bfv[2];
#pragma unroll
        for (int mt = 0; mt < 2; ++mt) {
          int r = wm * 32 + mt * 16 + l15;
          af[mt] = *(const bf16x8*)&Ap[r * 64 + ((u ^ (l15 & 7)) << 3)];
        }
#pragma unroll
        for (int nt = 0; nt < 2; ++nt) {
          int r = wn * 32 + nt * 16 + l15;
          bfv[nt] = *(const bf16x8*)&Bp[r * 64 + ((u ^ (l15 & 7)) << 3)];
        }
#pragma unroll
        for (int mt = 0; mt < 2; ++mt)
#pragma unroll
          for (int nt = 0; nt < 2; ++nt)
            acc[mt][nt] = __builtin_amdgcn_mfma_f32_16x16x32_bf16(af[mt], bfv[nt], acc[mt][nt], 0, 0, 0);
      }
    }
  }

#pragma unroll
  for (int mt = 0; mt < 2; ++mt) {
    int mrow = tM + wm * 32 + mt * 16 + quad * 4;
#pragma unroll
    for (int nt = 0; nt < 2; ++nt) {
      int ncol = tN + wn * 32 + nt * 16 + l15;
      float bs = bias[ncol];
#pragma unroll
      for (int r = 0; r < 4; ++r) {
        int m = mrow + r;
        int p = m & 1023;
        if (p < 961) {
          size_t o = (size_t)(m + 63) * 1024 + (size_t)ncol;
          out[o] = acc[mt][nt][r] + bs + resid[o];
        }
      }
    }
  }
}

// ---------------- attention: one block per (b, c, head), 4 blocks/CU --------
// T2 swizzle on Q/K (worth ~11 us). T14 on V: the first two V fragment sets
// (bvA=kt2 0, bvB=kt2 1) are issued BEFORE the softmax phase (~400 VALU cyc
// covers their L2/L3 latency); in-loop reloads issue immediately after each
// buffer's last MFMA, maximizing issue->consume distance at zero extra VGPR.
__launch_bounds__(256, 4)
__global__ void cca_attn_k(const unsigned short* __restrict__ Q,   // [4096][1024]
                           const unsigned short* __restrict__ KV,  // K cols + VT region
                           unsigned short* __restrict__ O) {       // [4096][1024]
  __shared__ unsigned short smemA[64 * 64 + 256 * 64];   // Qsh|Ksh, aliased by Psh
  unsigned short* Qsh = smemA;
  unsigned short* Ksh = smemA + 64 * 64;
  unsigned short* Psh = smemA;                // alias (post-barrier); 64*264 fits
  int bch = blockIdx.x;
  int hh = bch & 15, c = (bch >> 4) & 15, b = bch >> 8;
  int t = threadIdx.x, lane = t & 63, wv = t >> 6;
  int l15 = lane & 15, quad = lane >> 4;
  size_t qbase = (size_t)b * 1024 + (size_t)c * 64;
  size_t kvbase = (size_t)b * 4096 + (size_t)c * 256;
  int hoff = hh * 64;
  const unsigned short* vbase2 =
      KV + (size_t)(b * 16 + c) * 524288 + 1024 + (size_t)hh * 32768;

  {
    int rowi = lane >> 3, chk = lane & 7;
    int gchk2 = chk ^ rowi;                // pre-swizzled source unit (T2)
#pragma unroll
    for (int ii = 0; ii < 2; ++ii) {
      int seg = wv + ii * 4;
      int row = seg * 8 + rowi;            // row&7 == rowi
      gl2lds16(Q + (qbase + row) * 1024 + hoff + gchk2 * 8, Qsh + seg * 512);
    }
#pragma unroll
    for (int ii = 0; ii < 8; ++ii) {
      int seg = wv + ii * 4;
      int row = seg * 8 + rowi;
      gl2lds16(KV + (kvbase + row) * 2048 + hoff + gchk2 * 8, Ksh + seg * 512);
    }
  }
  __syncthreads();

  floatx4 st[16];
#pragma unroll
  for (int i = 0; i < 16; ++i) st[i] = zero4();
  // swizzled fragment reads: LDS unit (u ^ (row&7)), row&7 == l15&7
  int sw0 = (quad ^ (l15 & 7)) << 3;         // u = quad
  int sw1 = ((quad + 4) ^ (l15 & 7)) << 3;   // u = quad+4
  bf16x8 a0 = *(const bf16x8*)&Qsh[(wv * 16 + l15) * 64 + sw0];
  bf16x8 a1 = *(const bf16x8*)&Qsh[(wv * 16 + l15) * 64 + sw1];
  __builtin_amdgcn_s_setprio(1);
#pragma unroll
  for (int kt = 0; kt < 16; ++kt) {
    bf16x8 b0 = *(const bf16x8*)&Ksh[(kt * 16 + l15) * 64 + sw0];
    bf16x8 b1 = *(const bf16x8*)&Ksh[(kt * 16 + l15) * 64 + sw1];
    st[kt] = __builtin_amdgcn_mfma_f32_16x16x32_bf16(a0, b0, st[kt], 0, 0, 0);
    st[kt] = __builtin_amdgcn_mfma_f32_16x16x32_bf16(a1, b1, st[kt], 0, 0, 0);
  }
  __builtin_amdgcn_s_setprio(0);
  __syncthreads();   // Qsh/Ksh dead; Psh may alias

  // V fragment direct-global load (L3-resident VT image).
  auto vload = [&](int kt2, int nt) -> bf16x8 {
    int vrow = nt * 16 + l15;
    int u = kt2 * 4 + quad;
    int i = vrow * 256 + ((u ^ (vrow & 7)) << 3);
    return *(const bf16x8*)(vbase2 + i + (i & ~1023));
  };

  // T14: issue first two V pair-sets now; softmax below hides their latency.
  bf16x8 bvA[4], bvB[4];
#pragma unroll
  for (int nt = 0; nt < 4; ++nt) bvA[nt] = vload(0, nt);
#pragma unroll
  for (int nt = 0; nt < 4; ++nt) bvB[nt] = vload(1, nt);

  const float scale = 0.125f;  // 1/sqrt(64)
#pragma unroll
  for (int r = 0; r < 4; ++r) {
    float mx = -1e30f;
#pragma unroll
    for (int kt = 0; kt < 16; ++kt) mx = fmaxf(mx, st[kt][r]);
    mx = fmaxf(mx, __shfl_xor(mx, 1));
    mx = fmaxf(mx, __shfl_xor(mx, 2));
    mx = fmaxf(mx, __shfl_xor(mx, 4));
    mx = fmaxf(mx, __shfl_xor(mx, 8));
    float sum = 0.f;
#pragma unroll
    for (int kt = 0; kt < 16; ++kt) {
      float e = __expf((st[kt][r] - mx) * scale);
      st[kt][r] = e;
      sum += e;
    }
    sum += __shfl_xor(sum, 1);
    sum += __shfl_xor(sum, 2);
    sum += __shfl_xor(sum, 4);
    sum += __shfl_xor(sum, 8);
    float inv = 1.0f / sum;
    int prow = wv * 16 + quad * 4 + r;
#pragma unroll
    for (int kt = 0; kt < 16; ++kt)
      Psh[prow * 264 + kt * 16 + l15] = (unsigned short)f2bf(st[kt][r] * inv);
  }
  __syncthreads();   // P visible to all waves

  floatx4 ot[4];
#pragma unroll
  for (int nt = 0; nt < 4; ++nt) ot[nt] = zero4();
#pragma unroll
  for (int kt2 = 0; kt2 < 8; kt2 += 2) {
    bf16x8 ap0 = *(const bf16x8*)&Psh[(wv * 16 + l15) * 264 + kt2 * 32 + quad * 8];
    __builtin_amdgcn_s_setprio(1);
#pragma unroll
    for (int nt = 0; nt < 4; ++nt)
      ot[nt] = __builtin_amdgcn_mfma_f32_16x16x32_bf16(ap0, bvA[nt], ot[nt], 0, 0, 0);
    __builtin_amdgcn_s_setprio(0);
    if (kt2 + 2 < 8) {               // reload bvA right after its last use
#pragma unroll
      for (int nt = 0; nt < 4; ++nt) bvA[nt] = vload(kt2 + 2, nt);
    }
    bf16x8 ap1 = *(const bf16x8*)&Psh[(wv * 16 + l15) * 264 + (kt2 + 1) * 32 + quad * 8];
    __builtin_amdgcn_s_setprio(1);
#pragma unroll
    for (int nt = 0; nt < 4; ++nt)
      ot[nt] = __builtin_amdgcn_mfma_f32_16x16x32_bf16(ap1, bvB[nt], ot[nt], 0, 0, 0);
    __builtin_amdgcn_s_setprio(0);
    if (kt2 + 3 < 8) {               // reload bvB right after its last use
#pragma unroll
      for (int nt = 0; nt < 4; ++nt) bvB[nt] = vload(kt2 + 3, nt);
    }
  }
#pragma unroll
  for (int nt = 0; nt < 4; ++nt) {
#pragma unroll
    for (int r = 0; r < 4; ++r) {
      int i = wv * 16 + quad * 4 + r;
      int dcol = hoff + nt * 16 + l15;
      O[(qbase + i) * 1024 + dcol] = (unsigned short)f2bf(ot[nt][r]);
    }
  }
}

extern "C" void kernel_launch(void* const* d_in, const int* in_sizes, int n_in,
                              void* d_out, int out_size, void* d_ws, size_t ws_size,
                              hipStream_t stream) {
  const float* h  = (const float*)d_in[0];
  const float* e  = (const float*)d_in[1];
  const float* g  = (const float*)d_in[2];
  const float* Wq = (const float*)d_in[3];
  const float* bq = (const float*)d_in[4];
  const float* Wk = (const float*)d_in[5];
  const float* bk = (const float*)d_in[6];
  const float* Wv = (const float*)d_in[7];
  const float* bv = (const float*)d_in[8];
  const float* Wo = (const float*)d_in[9];
  const float* bo = (const float*)d_in[10];
  float* out = (float*)d_out;

  unsigned short* ws   = (unsigned short*)d_ws;
  unsigned short* hn   = ws;                                   // 4096*1024
  unsigned short* WqT  = hn   + (size_t)4096 * 1024;           // 1024*1024
  unsigned short* WkvT = WqT  + (size_t)1024 * 1024;           // 2048*1024
  unsigned short* WoT  = WkvT + (size_t)2048 * 1024;           // 1024*1024
  unsigned short* Qb   = WoT  + (size_t)1024 * 1024;           // 4096*1024
  unsigned short* KVb  = Qb   + (size_t)4096 * 1024;           // 16384*2048
  unsigned short* Ob   = KVb  + (size_t)16384 * 2048;          // 4096*1024
  unsigned short* eb   = Ob   + (size_t)4096 * 1024;           // 16384*1024

  cca_prep_k<<<4159, 256, 0, stream>>>(
      Wq, Wk, Wv, Wo, WqT, WkvT, WkvT + (size_t)1024 * 1024, WoT,
      e, eb, h, g, hn, out);

  cca_gemmQKV_k<<<2304, 256, 0, stream>>>(eb, WkvT, bk, bv, KVb,
                                          hn, WqT, bq, Qb);

  cca_attn_k<<<1024, 256, 0, stream>>>(Qb, KVb, Ob);

  cca_gemmO_k<<<dim3(64, 16), 256, 0, stream>>>(Ob, WoT, bo, h, out);
}